// Round 2
// baseline (444.320 us; speedup 1.0000x reference)
//
#include <hip/hip_runtime.h>

#define N_NODES 50000
#define N_EDGES 800000
#define F 64
#define NPAD 50048   // N_NODES padded to multiple of 64

// ======================= CSR-gather path =======================

// ---- K1: deg[row] += w (fp32) and cnt[col]++ (int), skipping self-loops ----
__global__ __launch_bounds__(256) void degcnt_kernel(const int* __restrict__ ei,
                                                     const float* __restrict__ ew,
                                                     float* __restrict__ deg,
                                                     int* __restrict__ cnt) {
    int e = blockIdx.x * blockDim.x + threadIdx.x;
    if (e >= N_EDGES) return;
    int r = ei[e];
    int c = ei[N_EDGES + e];
    if (r != c) {
        atomicAdd(&deg[r], ew[e]);
        atomicAdd(&cnt[c], 1);
    }
}

// ---- K2 (single block): dinv = rsqrt(deg) ; exclusive scan cnt -> offs,cursor ----
__global__ __launch_bounds__(256) void scan_kernel(const float* __restrict__ deg,
                                                   float* __restrict__ dinv,
                                                   const int* __restrict__ cnt,
                                                   int* __restrict__ offs,
                                                   int* __restrict__ cursor) {
    __shared__ int wsum[4];
    __shared__ int sbase;
    const int t = threadIdx.x;
    const int lane = t & 63, wid = t >> 6;

    for (int i = t; i < N_NODES; i += 256) {
        float d = deg[i];
        dinv[i] = (d > 0.0f) ? rsqrtf(d) : 0.0f;
    }
    if (t == 0) sbase = 0;
    __syncthreads();

    for (int c0 = 0; c0 < N_NODES; c0 += 256) {
        int i = c0 + t;
        int v = (i < N_NODES) ? cnt[i] : 0;
        int s = v;  // inclusive wave scan
#pragma unroll
        for (int d = 1; d < 64; d <<= 1) {
            int u = __shfl_up(s, d);
            if (lane >= d) s += u;
        }
        if (lane == 63) wsum[wid] = s;
        __syncthreads();
        int wbase = 0;
        for (int w = 0; w < wid; ++w) wbase += wsum[w];
        int base = sbase;
        int excl = base + wbase + s - v;
        if (i < N_NODES) { offs[i] = excl; cursor[i] = excl; }
        __syncthreads();
        if (t == 255) sbase = base + wbase + s;  // total so far
    }
    __syncthreads();
    if (t == 0) offs[N_NODES] = sbase;
}

// ---- K3: counting-sort placement of (row, norm) by destination col ----
__global__ __launch_bounds__(256) void fill_kernel(const int* __restrict__ ei,
                                                   const float* __restrict__ ew,
                                                   const float* __restrict__ dinv,
                                                   int* __restrict__ cursor,
                                                   int* __restrict__ srcRow,
                                                   float* __restrict__ srcW) {
    int e = blockIdx.x * blockDim.x + threadIdx.x;
    if (e >= N_EDGES) return;
    int r = ei[e];
    int c = ei[N_EDGES + e];
    if (r == c) return;
    float nrm = -dinv[r] * ew[e] * dinv[c];
    int p = atomicAdd(&cursor[c], 1);
    srcRow[p] = r;
    srcW[p] = nrm;
}

// ---- K4: per-node gather, one wave per node, no atomics ----
__global__ __launch_bounds__(256) void gather_kernel(const int* __restrict__ offs,
                                                     const int* __restrict__ srcRow,
                                                     const float* __restrict__ srcW,
                                                     const float* __restrict__ x,
                                                     float* __restrict__ S) {
    int n = blockIdx.x * 4 + (threadIdx.x >> 6);
    int lane = threadIdx.x & 63;
    if (n >= N_NODES) return;
    int p = offs[n], end = offs[n + 1];
    float acc = 0.0f;
    for (; p + 2 <= end; p += 2) {
        int r0 = srcRow[p], r1 = srcRow[p + 1];
        float w0 = srcW[p], w1 = srcW[p + 1];
        float v0 = x[r0 * F + lane];
        float v1 = x[r1 * F + lane];
        acc = fmaf(w0, v0, acc);
        acc = fmaf(w1, v1, acc);
    }
    if (p < end) acc = fmaf(srcW[p], x[srcRow[p] * F + lane], acc);
    S[n * F + lane] = acc;
}

// ======================= fallback scatter path =======================
__global__ __launch_bounds__(256) void deg_kernel(const int* __restrict__ ei,
                                                  const float* __restrict__ ew,
                                                  float* __restrict__ deg) {
    int e = blockIdx.x * blockDim.x + threadIdx.x;
    if (e >= N_EDGES) return;
    int r = ei[e];
    int c = ei[N_EDGES + e];
    if (r != c) atomicAdd(&deg[r], ew[e]);
}

__global__ __launch_bounds__(256) void dinv_kernel(const float* __restrict__ deg,
                                                   float* __restrict__ dinv) {
    int n = blockIdx.x * blockDim.x + threadIdx.x;
    if (n >= N_NODES) return;
    float d = deg[n];
    dinv[n] = (d > 0.0f) ? rsqrtf(d) : 0.0f;
}

__global__ __launch_bounds__(256) void scatter_kernel(const int* __restrict__ ei,
                                                      const float* __restrict__ ew,
                                                      const float* __restrict__ x,
                                                      const float* __restrict__ dinv,
                                                      float* S) {
    int e = blockIdx.x * 4 + (threadIdx.x >> 6);
    int lane = threadIdx.x & 63;
    if (e >= N_EDGES) return;
    int r = ei[e];
    int c = ei[N_EDGES + e];
    if (r == c) return;
    float nrm = -dinv[r] * ew[e] * dinv[c];
    atomicAdd(&S[c * F + lane], nrm * x[r * F + lane]);
}

// ======================= K5: fused GEMMs + gating + output =======================
__global__ __launch_bounds__(256) void fused_kernel(
    const float* __restrict__ x, float* sOut,
    const float* __restrict__ Wxz0, const float* __restrict__ Wxz1,
    const float* __restrict__ Wxh0, const float* __restrict__ Wxh1,
    const float* __restrict__ bxz, const float* __restrict__ bhz,
    const float* __restrict__ bxh, const float* __restrict__ bhh,
    const float* __restrict__ Wlin, const float* __restrict__ blin) {
    __shared__ float As[64][136];
    __shared__ float Wc[64][64];

    const int t = threadIdx.x;
    const int n0 = blockIdx.x * 64;
    const int ti = t >> 4;
    const int tj = t & 15;

#pragma unroll
    for (int r = 0; r < 4; ++r) {
        int idx = r * 256 + t;
        int n = idx >> 4, kq = idx & 15;
        int gn = n0 + n;
        float4 vx = make_float4(0.f, 0.f, 0.f, 0.f);
        float4 vs = vx;
        if (gn < N_NODES) {
            vx = *(const float4*)&x[gn * F + kq * 4];
            vs = *(const float4*)&sOut[gn * F + kq * 4];
        }
        *(float4*)&As[n][kq * 4] = vx;
        *(float4*)&As[n][64 + kq * 4] = vs;
    }

    float zacc[4][4], hacc[4][4];
#pragma unroll
    for (int j = 0; j < 4; ++j) {
        float bz = bxz[tj * 4 + j] + bhz[tj * 4 + j];
        float bh = bxh[tj * 4 + j] + bhh[tj * 4 + j];
#pragma unroll
        for (int i = 0; i < 4; ++i) { zacc[i][j] = bz; hacc[i][j] = bh; }
    }

    for (int kc = 0; kc < 4; ++kc) {
        if (kc) __syncthreads();
#pragma unroll
        for (int r = 0; r < 2; ++r) {
            int idx = r * 256 + t;
            int kk = idx >> 4;
            int kq = idx & 15;
            int kg = kc * 32 + kk;
            const float* srcz = (kg < 64) ? (Wxz0 + kg * F) : (Wxz1 + (kg - 64) * F);
            const float* srch = (kg < 64) ? (Wxh0 + kg * F) : (Wxh1 + (kg - 64) * F);
            *(float4*)&Wc[kk][kq * 4]      = *(const float4*)(srcz + kq * 4);
            *(float4*)&Wc[32 + kk][kq * 4] = *(const float4*)(srch + kq * 4);
        }
        __syncthreads();
#pragma unroll
        for (int k4 = 0; k4 < 8; ++k4) {
            float a_[4][4];
#pragma unroll
            for (int i = 0; i < 4; ++i) {
                float4 v = *(const float4*)&As[ti * 4 + i][kc * 32 + k4 * 4];
                a_[i][0] = v.x; a_[i][1] = v.y; a_[i][2] = v.z; a_[i][3] = v.w;
            }
#pragma unroll
            for (int kk = 0; kk < 4; ++kk) {
                float4 bz = *(const float4*)&Wc[k4 * 4 + kk][tj * 4];
                float4 bh = *(const float4*)&Wc[32 + k4 * 4 + kk][tj * 4];
#pragma unroll
                for (int i = 0; i < 4; ++i) {
                    float a = a_[i][kk];
                    zacc[i][0] += a * bz.x; zacc[i][1] += a * bz.y;
                    zacc[i][2] += a * bz.z; zacc[i][3] += a * bz.w;
                    hacc[i][0] += a * bh.x; hacc[i][1] += a * bh.y;
                    hacc[i][2] += a * bh.z; hacc[i][3] += a * bh.w;
                }
            }
        }
    }

    float R_[4][4];
#pragma unroll
    for (int i = 0; i < 4; ++i)
#pragma unroll
        for (int j = 0; j < 4; ++j) {
            float zz = 1.0f / (1.0f + __expf(-zacc[i][j]));
            float hh = tanhf(hacc[i][j]);
            R_[i][j] = fmaxf((1.0f - zz) * hh, 0.0f);
        }

    __syncthreads();
#pragma unroll
    for (int i = 0; i < 4; ++i) {
        float4 v = make_float4(R_[i][0], R_[i][1], R_[i][2], R_[i][3]);
        *(float4*)&As[ti * 4 + i][tj * 4] = v;
    }
#pragma unroll
    for (int r = 0; r < 4; ++r) {
        int idx = r * 256 + t;
        int kk = idx >> 4, kq = idx & 15;
        *(float4*)&Wc[kk][kq * 4] = *(const float4*)&Wlin[kk * F + kq * 4];
    }
    __syncthreads();

    float oacc[4][4];
#pragma unroll
    for (int j = 0; j < 4; ++j) {
        float bl = blin[tj * 4 + j];
#pragma unroll
        for (int i = 0; i < 4; ++i) oacc[i][j] = bl;
    }
#pragma unroll
    for (int k4 = 0; k4 < 16; ++k4) {
        float a_[4][4];
#pragma unroll
        for (int i = 0; i < 4; ++i) {
            float4 v = *(const float4*)&As[ti * 4 + i][k4 * 4];
            a_[i][0] = v.x; a_[i][1] = v.y; a_[i][2] = v.z; a_[i][3] = v.w;
        }
#pragma unroll
        for (int kk = 0; kk < 4; ++kk) {
            float4 b = *(const float4*)&Wc[k4 * 4 + kk][tj * 4];
#pragma unroll
            for (int i = 0; i < 4; ++i) {
                float a = a_[i][kk];
                oacc[i][0] += a * b.x; oacc[i][1] += a * b.y;
                oacc[i][2] += a * b.z; oacc[i][3] += a * b.w;
            }
        }
    }
#pragma unroll
    for (int i = 0; i < 4; ++i) {
        int gn = n0 + ti * 4 + i;
        if (gn < N_NODES) {
            float4 v = make_float4(oacc[i][0], oacc[i][1], oacc[i][2], oacc[i][3]);
            *(float4*)&sOut[gn * F + tj * 4] = v;
        }
    }
}

extern "C" void kernel_launch(void* const* d_in, const int* in_sizes, int n_in,
                              void* d_out, int out_size, void* d_ws, size_t ws_size,
                              hipStream_t stream) {
    const float* x    = (const float*)d_in[0];
    const int*   ei   = (const int*)d_in[1];
    const float* ew   = (const float*)d_in[2];
    const float* Wxz0 = (const float*)d_in[3];
    const float* Wxz1 = (const float*)d_in[4];
    const float* bxz  = (const float*)d_in[5];
    const float* bhz  = (const float*)d_in[8];
    const float* Wxh0 = (const float*)d_in[15];
    const float* Wxh1 = (const float*)d_in[16];
    const float* bxh  = (const float*)d_in[17];
    const float* bhh  = (const float*)d_in[20];
    const float* Wlin = (const float*)d_in[21];
    const float* blin = (const float*)d_in[22];
    float* outp = (float*)d_out;  // doubles as S buffer

    // ws layout: [deg | cnt | dinv | offs | cursor | srcRow | srcW]
    float* deg   = (float*)d_ws;
    int*   cnt   = (int*)(deg + NPAD);
    float* dinv  = (float*)(cnt + NPAD);
    int*   offs  = (int*)(dinv + NPAD);
    int*   curs  = offs + NPAD;
    int*   srcR  = curs + NPAD;
    float* srcW  = (float*)(srcR + N_EDGES);
    size_t needed = (size_t)NPAD * 5 * 4 + (size_t)N_EDGES * 8 + 256;

    if (ws_size >= needed) {
        hipMemsetAsync(d_ws, 0, (size_t)NPAD * 2 * sizeof(float), stream);  // deg + cnt
        degcnt_kernel<<<(N_EDGES + 255) / 256, 256, 0, stream>>>(ei, ew, deg, cnt);
        scan_kernel<<<1, 256, 0, stream>>>(deg, dinv, cnt, offs, curs);
        fill_kernel<<<(N_EDGES + 255) / 256, 256, 0, stream>>>(ei, ew, dinv, curs, srcR, srcW);
        gather_kernel<<<(N_NODES + 3) / 4, 256, 0, stream>>>(offs, srcR, srcW, x, outp);
    } else {
        hipMemsetAsync(d_ws, 0, N_NODES * sizeof(float), stream);
        hipMemsetAsync(d_out, 0, (size_t)N_NODES * F * sizeof(float), stream);
        deg_kernel<<<(N_EDGES + 255) / 256, 256, 0, stream>>>(ei, ew, deg);
        dinv_kernel<<<(N_NODES + 255) / 256, 256, 0, stream>>>(deg, (float*)(deg + N_NODES));
        scatter_kernel<<<N_EDGES / 4, 256, 0, stream>>>(ei, ew, x, (float*)(deg + N_NODES), outp);
    }
    fused_kernel<<<(N_NODES + 63) / 64, 256, 0, stream>>>(
        x, outp, Wxz0, Wxz1, Wxh0, Wxh1, bxz, bhz, bxh, bhh, Wlin, blin);
}

// Round 3
// 274.242 us; speedup vs baseline: 1.6202x; 1.6202x over previous
//
#include <hip/hip_runtime.h>

#define N_NODES 50000
#define N_EDGES 800000
#define F 64
#define NPAD 50048                    // N_NODES padded to multiple of 64
#define NCHUNK ((N_NODES + 255) / 256)  // 196

// ---- K1: deg[row] += w (fp32) and cnt[col]++ (int), skipping self-loops ----
__global__ __launch_bounds__(256) void degcnt_kernel(const int* __restrict__ ei,
                                                     const float* __restrict__ ew,
                                                     float* __restrict__ deg,
                                                     int* __restrict__ cnt) {
    int e = blockIdx.x * blockDim.x + threadIdx.x;
    if (e >= N_EDGES) return;
    int r = ei[e];
    int c = ei[N_EDGES + e];
    if (r != c) {
        atomicAdd(&deg[r], ew[e]);
        atomicAdd(&cnt[c], 1);
    }
}

// ---- K2a: dinv = rsqrt(deg); per-chunk sum of cnt -> bsum ----
__global__ __launch_bounds__(256) void reduce_kernel(const float* __restrict__ deg,
                                                     float* __restrict__ dinv,
                                                     const int* __restrict__ cnt,
                                                     int* __restrict__ bsum) {
    __shared__ int wsum[4];
    const int t = threadIdx.x;
    const int i = blockIdx.x * 256 + t;
    const int lane = t & 63, wid = t >> 6;

    if (i < N_NODES) {
        float d = deg[i];
        dinv[i] = (d > 0.0f) ? rsqrtf(d) : 0.0f;
    }
    int v = (i < N_NODES) ? cnt[i] : 0;
#pragma unroll
    for (int d = 32; d > 0; d >>= 1) v += __shfl_down(v, d);
    if (lane == 0) wsum[wid] = v;
    __syncthreads();
    if (t == 0) bsum[blockIdx.x] = wsum[0] + wsum[1] + wsum[2] + wsum[3];
}

// ---- K2b (1 block): exclusive scan of bsum -> bbase; total -> offsN ----
__global__ __launch_bounds__(256) void scanb_kernel(const int* __restrict__ bsum,
                                                    int* __restrict__ bbase,
                                                    int* __restrict__ offsN) {
    __shared__ int wsum[4];
    const int t = threadIdx.x;
    const int lane = t & 63, wid = t >> 6;
    int v = (t < NCHUNK) ? bsum[t] : 0;
    int s = v;
#pragma unroll
    for (int d = 1; d < 64; d <<= 1) {
        int u = __shfl_up(s, d);
        if (lane >= d) s += u;
    }
    if (lane == 63) wsum[wid] = s;
    __syncthreads();
    int wbase = 0;
    for (int w = 0; w < wid; ++w) wbase += wsum[w];
    if (t < NCHUNK) bbase[t] = wbase + s - v;
    if (t == 255) offsN[0] = wbase + s;
}

// ---- K2c: per-chunk exclusive scan + bbase -> offs, cursor ----
__global__ __launch_bounds__(256) void scanc_kernel(const int* __restrict__ cnt,
                                                    const int* __restrict__ bbase,
                                                    int* __restrict__ offs,
                                                    int* __restrict__ cursor) {
    __shared__ int wsum[4];
    const int t = threadIdx.x;
    const int i = blockIdx.x * 256 + t;
    const int lane = t & 63, wid = t >> 6;
    int v = (i < N_NODES) ? cnt[i] : 0;
    int s = v;
#pragma unroll
    for (int d = 1; d < 64; d <<= 1) {
        int u = __shfl_up(s, d);
        if (lane >= d) s += u;
    }
    if (lane == 63) wsum[wid] = s;
    __syncthreads();
    int wbase = 0;
    for (int w = 0; w < wid; ++w) wbase += wsum[w];
    int excl = bbase[blockIdx.x] + wbase + s - v;
    if (i < N_NODES) { offs[i] = excl; cursor[i] = excl; }
}

// ---- K3: counting-sort placement of (row, norm) by destination col ----
__global__ __launch_bounds__(256) void fill_kernel(const int* __restrict__ ei,
                                                   const float* __restrict__ ew,
                                                   const float* __restrict__ dinv,
                                                   int* __restrict__ cursor,
                                                   int* __restrict__ srcRow,
                                                   float* __restrict__ srcW) {
    int e = blockIdx.x * blockDim.x + threadIdx.x;
    if (e >= N_EDGES) return;
    int r = ei[e];
    int c = ei[N_EDGES + e];
    if (r == c) return;
    float nrm = -dinv[r] * ew[e] * dinv[c];
    int p = atomicAdd(&cursor[c], 1);
    srcRow[p] = r;
    srcW[p] = nrm;
}

// ---- K4: per-node gather, one wave per node, no atomics ----
__global__ __launch_bounds__(256) void gather_kernel(const int* __restrict__ offs,
                                                     const int* __restrict__ srcRow,
                                                     const float* __restrict__ srcW,
                                                     const float* __restrict__ x,
                                                     float* __restrict__ S) {
    int n = blockIdx.x * 4 + (threadIdx.x >> 6);
    int lane = threadIdx.x & 63;
    if (n >= N_NODES) return;
    int p = offs[n], end = offs[n + 1];
    float acc = 0.0f;
    for (; p + 2 <= end; p += 2) {
        int r0 = srcRow[p], r1 = srcRow[p + 1];
        float w0 = srcW[p], w1 = srcW[p + 1];
        float v0 = x[r0 * F + lane];
        float v1 = x[r1 * F + lane];
        acc = fmaf(w0, v0, acc);
        acc = fmaf(w1, v1, acc);
    }
    if (p < end) acc = fmaf(srcW[p], x[srcRow[p] * F + lane], acc);
    S[n * F + lane] = acc;
}

// ---- K5: fused GEMMs + gating + output projection ----
__global__ __launch_bounds__(256) void fused_kernel(
    const float* __restrict__ x, float* sOut,
    const float* __restrict__ Wxz0, const float* __restrict__ Wxz1,
    const float* __restrict__ Wxh0, const float* __restrict__ Wxh1,
    const float* __restrict__ bxz, const float* __restrict__ bhz,
    const float* __restrict__ bxh, const float* __restrict__ bhh,
    const float* __restrict__ Wlin, const float* __restrict__ blin) {
    __shared__ float As[64][136];
    __shared__ float Wc[64][64];

    const int t = threadIdx.x;
    const int n0 = blockIdx.x * 64;
    const int ti = t >> 4;
    const int tj = t & 15;

#pragma unroll
    for (int r = 0; r < 4; ++r) {
        int idx = r * 256 + t;
        int n = idx >> 4, kq = idx & 15;
        int gn = n0 + n;
        float4 vx = make_float4(0.f, 0.f, 0.f, 0.f);
        float4 vs = vx;
        if (gn < N_NODES) {
            vx = *(const float4*)&x[gn * F + kq * 4];
            vs = *(const float4*)&sOut[gn * F + kq * 4];
        }
        *(float4*)&As[n][kq * 4] = vx;
        *(float4*)&As[n][64 + kq * 4] = vs;
    }

    float zacc[4][4], hacc[4][4];
#pragma unroll
    for (int j = 0; j < 4; ++j) {
        float bz = bxz[tj * 4 + j] + bhz[tj * 4 + j];
        float bh = bxh[tj * 4 + j] + bhh[tj * 4 + j];
#pragma unroll
        for (int i = 0; i < 4; ++i) { zacc[i][j] = bz; hacc[i][j] = bh; }
    }

    for (int kc = 0; kc < 4; ++kc) {
        if (kc) __syncthreads();
#pragma unroll
        for (int r = 0; r < 2; ++r) {
            int idx = r * 256 + t;
            int kk = idx >> 4;
            int kq = idx & 15;
            int kg = kc * 32 + kk;
            const float* srcz = (kg < 64) ? (Wxz0 + kg * F) : (Wxz1 + (kg - 64) * F);
            const float* srch = (kg < 64) ? (Wxh0 + kg * F) : (Wxh1 + (kg - 64) * F);
            *(float4*)&Wc[kk][kq * 4]      = *(const float4*)(srcz + kq * 4);
            *(float4*)&Wc[32 + kk][kq * 4] = *(const float4*)(srch + kq * 4);
        }
        __syncthreads();
#pragma unroll
        for (int k4 = 0; k4 < 8; ++k4) {
            float a_[4][4];
#pragma unroll
            for (int i = 0; i < 4; ++i) {
                float4 v = *(const float4*)&As[ti * 4 + i][kc * 32 + k4 * 4];
                a_[i][0] = v.x; a_[i][1] = v.y; a_[i][2] = v.z; a_[i][3] = v.w;
            }
#pragma unroll
            for (int kk = 0; kk < 4; ++kk) {
                float4 bz = *(const float4*)&Wc[k4 * 4 + kk][tj * 4];
                float4 bh = *(const float4*)&Wc[32 + k4 * 4 + kk][tj * 4];
#pragma unroll
                for (int i = 0; i < 4; ++i) {
                    float a = a_[i][kk];
                    zacc[i][0] += a * bz.x; zacc[i][1] += a * bz.y;
                    zacc[i][2] += a * bz.z; zacc[i][3] += a * bz.w;
                    hacc[i][0] += a * bh.x; hacc[i][1] += a * bh.y;
                    hacc[i][2] += a * bh.z; hacc[i][3] += a * bh.w;
                }
            }
        }
    }

    float R_[4][4];
#pragma unroll
    for (int i = 0; i < 4; ++i)
#pragma unroll
        for (int j = 0; j < 4; ++j) {
            float zz = 1.0f / (1.0f + __expf(-zacc[i][j]));
            float hh = tanhf(hacc[i][j]);
            R_[i][j] = fmaxf((1.0f - zz) * hh, 0.0f);
        }

    __syncthreads();
#pragma unroll
    for (int i = 0; i < 4; ++i) {
        float4 v = make_float4(R_[i][0], R_[i][1], R_[i][2], R_[i][3]);
        *(float4*)&As[ti * 4 + i][tj * 4] = v;
    }
#pragma unroll
    for (int r = 0; r < 4; ++r) {
        int idx = r * 256 + t;
        int kk = idx >> 4, kq = idx & 15;
        *(float4*)&Wc[kk][kq * 4] = *(const float4*)&Wlin[kk * F + kq * 4];
    }
    __syncthreads();

    float oacc[4][4];
#pragma unroll
    for (int j = 0; j < 4; ++j) {
        float bl = blin[tj * 4 + j];
#pragma unroll
        for (int i = 0; i < 4; ++i) oacc[i][j] = bl;
    }
#pragma unroll
    for (int k4 = 0; k4 < 16; ++k4) {
        float a_[4][4];
#pragma unroll
        for (int i = 0; i < 4; ++i) {
            float4 v = *(const float4*)&As[ti * 4 + i][k4 * 4];
            a_[i][0] = v.x; a_[i][1] = v.y; a_[i][2] = v.z; a_[i][3] = v.w;
        }
#pragma unroll
        for (int kk = 0; kk < 4; ++kk) {
            float4 b = *(const float4*)&Wc[k4 * 4 + kk][tj * 4];
#pragma unroll
            for (int i = 0; i < 4; ++i) {
                float a = a_[i][kk];
                oacc[i][0] += a * b.x; oacc[i][1] += a * b.y;
                oacc[i][2] += a * b.z; oacc[i][3] += a * b.w;
            }
        }
    }
#pragma unroll
    for (int i = 0; i < 4; ++i) {
        int gn = n0 + ti * 4 + i;
        if (gn < N_NODES) {
            float4 v = make_float4(oacc[i][0], oacc[i][1], oacc[i][2], oacc[i][3]);
            *(float4*)&sOut[gn * F + tj * 4] = v;
        }
    }
}

extern "C" void kernel_launch(void* const* d_in, const int* in_sizes, int n_in,
                              void* d_out, int out_size, void* d_ws, size_t ws_size,
                              hipStream_t stream) {
    const float* x    = (const float*)d_in[0];
    const int*   ei   = (const int*)d_in[1];
    const float* ew   = (const float*)d_in[2];
    const float* Wxz0 = (const float*)d_in[3];
    const float* Wxz1 = (const float*)d_in[4];
    const float* bxz  = (const float*)d_in[5];
    const float* bhz  = (const float*)d_in[8];
    const float* Wxh0 = (const float*)d_in[15];
    const float* Wxh1 = (const float*)d_in[16];
    const float* bxh  = (const float*)d_in[17];
    const float* bhh  = (const float*)d_in[20];
    const float* Wlin = (const float*)d_in[21];
    const float* blin = (const float*)d_in[22];
    float* outp = (float*)d_out;  // doubles as S buffer

    // ws layout: [deg | cnt | dinv | offs(+1) | cursor | bsum | bbase | srcRow | srcW]
    float* deg   = (float*)d_ws;
    int*   cnt   = (int*)(deg + NPAD);
    float* dinv  = (float*)(cnt + NPAD);
    int*   offs  = (int*)(dinv + NPAD);
    int*   curs  = offs + NPAD;        // offs uses N_NODES+1 < NPAD
    int*   bsum  = curs + NPAD;
    int*   bbase = bsum + 256;
    int*   srcR  = bbase + 256;
    float* srcW  = (float*)(srcR + N_EDGES);
    size_t needed = (size_t)NPAD * 5 * 4 + 2048 + (size_t)N_EDGES * 8 + 256;

    if (ws_size >= needed) {
        hipMemsetAsync(d_ws, 0, (size_t)NPAD * 2 * sizeof(float), stream);  // deg + cnt
        degcnt_kernel<<<(N_EDGES + 255) / 256, 256, 0, stream>>>(ei, ew, deg, cnt);
        reduce_kernel<<<NCHUNK, 256, 0, stream>>>(deg, dinv, cnt, bsum);
        scanb_kernel<<<1, 256, 0, stream>>>(bsum, bbase, &offs[N_NODES]);
        scanc_kernel<<<NCHUNK, 256, 0, stream>>>(cnt, bbase, offs, curs);
        fill_kernel<<<(N_EDGES + 255) / 256, 256, 0, stream>>>(ei, ew, dinv, curs, srcR, srcW);
        gather_kernel<<<(N_NODES + 3) / 4, 256, 0, stream>>>(offs, srcR, srcW, x, outp);
    } else {
        // fallback: direct atomic scatter into d_out
        hipMemsetAsync(d_ws, 0, (size_t)NPAD * 3 * sizeof(float), stream);
        hipMemsetAsync(d_out, 0, (size_t)N_NODES * F * sizeof(float), stream);
        degcnt_kernel<<<(N_EDGES + 255) / 256, 256, 0, stream>>>(ei, ew, deg, cnt);
        reduce_kernel<<<NCHUNK, 256, 0, stream>>>(deg, dinv, cnt, (int*)(dinv + NPAD));
        // reuse scatter via gather path impossible; do per-edge atomic adds
        // (simple scatter kernel inline)
        struct L {};
        // fallback scatter
        extern __global__ void scatter_fb(const int*, const float*, const float*,
                                          const float*, float*);
        scatter_fb<<<N_EDGES / 4, 256, 0, stream>>>(ei, ew, x, dinv, outp);
    }
    fused_kernel<<<(N_NODES + 63) / 64, 256, 0, stream>>>(
        x, outp, Wxz0, Wxz1, Wxh0, Wxh1, bxz, bhz, bxh, bhh, Wlin, blin);
}

// fallback scatter definition (kept out of hot path)
__global__ __launch_bounds__(256) void scatter_fb(const int* __restrict__ ei,
                                                  const float* __restrict__ ew,
                                                  const float* __restrict__ x,
                                                  const float* __restrict__ dinv,
                                                  float* S) {
    int e = blockIdx.x * 4 + (threadIdx.x >> 6);
    int lane = threadIdx.x & 63;
    if (e >= N_EDGES) return;
    int r = ei[e];
    int c = ei[N_EDGES + e];
    if (r == c) return;
    float nrm = -dinv[r] * ew[e] * dinv[c];
    atomicAdd(&S[c * F + lane], nrm * x[r * F + lane]);
}

// Round 4
// 218.262 us; speedup vs baseline: 2.0357x; 1.2565x over previous
//
#include <hip/hip_runtime.h>

#define N_NODES 50000
#define N_EDGES 800000
#define F 64
#define NPAD 50048                      // N_NODES padded to multiple of 64
#define NCHUNK ((N_NODES + 255) / 256)  // 196
#define BN 128                          // nodes per fused block
#define ASTRIDE 132                     // 128 + 4 pad (multiple of 4 for b128 align)

// ---- K1: deg[row] += w (fp32) and cnt[col]++ (int), skipping self-loops ----
__global__ __launch_bounds__(256) void degcnt_kernel(const int* __restrict__ ei,
                                                     const float* __restrict__ ew,
                                                     float* __restrict__ deg,
                                                     int* __restrict__ cnt) {
    int e = blockIdx.x * blockDim.x + threadIdx.x;
    if (e >= N_EDGES) return;
    int r = ei[e];
    int c = ei[N_EDGES + e];
    if (r != c) {
        atomicAdd(&deg[r], ew[e]);
        atomicAdd(&cnt[c], 1);
    }
}

// ---- K2a: dinv = rsqrt(deg); per-chunk sum of cnt -> bsum ----
__global__ __launch_bounds__(256) void reduce_kernel(const float* __restrict__ deg,
                                                     float* __restrict__ dinv,
                                                     const int* __restrict__ cnt,
                                                     int* __restrict__ bsum) {
    __shared__ int wsum[4];
    const int t = threadIdx.x;
    const int i = blockIdx.x * 256 + t;
    const int lane = t & 63, wid = t >> 6;

    if (i < N_NODES) {
        float d = deg[i];
        dinv[i] = (d > 0.0f) ? rsqrtf(d) : 0.0f;
    }
    int v = (i < N_NODES) ? cnt[i] : 0;
#pragma unroll
    for (int d = 32; d > 0; d >>= 1) v += __shfl_down(v, d);
    if (lane == 0) wsum[wid] = v;
    __syncthreads();
    if (t == 0) bsum[blockIdx.x] = wsum[0] + wsum[1] + wsum[2] + wsum[3];
}

// ---- K2b (1 block): exclusive scan of bsum -> bbase; total -> offsN ----
__global__ __launch_bounds__(256) void scanb_kernel(const int* __restrict__ bsum,
                                                    int* __restrict__ bbase,
                                                    int* __restrict__ offsN) {
    __shared__ int wsum[4];
    const int t = threadIdx.x;
    const int lane = t & 63, wid = t >> 6;
    int v = (t < NCHUNK) ? bsum[t] : 0;
    int s = v;
#pragma unroll
    for (int d = 1; d < 64; d <<= 1) {
        int u = __shfl_up(s, d);
        if (lane >= d) s += u;
    }
    if (lane == 63) wsum[wid] = s;
    __syncthreads();
    int wbase = 0;
    for (int w = 0; w < wid; ++w) wbase += wsum[w];
    if (t < NCHUNK) bbase[t] = wbase + s - v;
    if (t == 255) offsN[0] = wbase + s;
}

// ---- K2c: per-chunk exclusive scan + bbase -> offs, cursor ----
__global__ __launch_bounds__(256) void scanc_kernel(const int* __restrict__ cnt,
                                                    const int* __restrict__ bbase,
                                                    int* __restrict__ offs,
                                                    int* __restrict__ cursor) {
    __shared__ int wsum[4];
    const int t = threadIdx.x;
    const int i = blockIdx.x * 256 + t;
    const int lane = t & 63, wid = t >> 6;
    int v = (i < N_NODES) ? cnt[i] : 0;
    int s = v;
#pragma unroll
    for (int d = 1; d < 64; d <<= 1) {
        int u = __shfl_up(s, d);
        if (lane >= d) s += u;
    }
    if (lane == 63) wsum[wid] = s;
    __syncthreads();
    int wbase = 0;
    for (int w = 0; w < wid; ++w) wbase += wsum[w];
    int excl = bbase[blockIdx.x] + wbase + s - v;
    if (i < N_NODES) { offs[i] = excl; cursor[i] = excl; }
}

// ---- K3: counting-sort placement, packed (row, dinv[row]*w) float2 write ----
__global__ __launch_bounds__(256) void fill_kernel(const int* __restrict__ ei,
                                                   const float* __restrict__ ew,
                                                   const float* __restrict__ dinv,
                                                   int* __restrict__ cursor,
                                                   float2* __restrict__ srcRW) {
    int e = blockIdx.x * blockDim.x + threadIdx.x;
    if (e >= N_EDGES) return;
    int r = ei[e];
    int c = ei[N_EDGES + e];
    if (r == c) return;
    float nrm = dinv[r] * ew[e];     // -dinv[c] folded into gather epilogue
    int p = atomicAdd(&cursor[c], 1);
    srcRW[p] = make_float2(__int_as_float(r), nrm);
}

// ---- K4: per-node gather, one wave per node, no atomics ----
__global__ __launch_bounds__(256) void gather_kernel(const int* __restrict__ offs,
                                                     const float2* __restrict__ srcRW,
                                                     const float* __restrict__ x,
                                                     const float* __restrict__ dinv,
                                                     float* __restrict__ S) {
    int n = blockIdx.x * 4 + (threadIdx.x >> 6);
    int lane = threadIdx.x & 63;
    if (n >= N_NODES) return;
    int p = offs[n], end = offs[n + 1];
    float acc = 0.0f;
    for (; p + 4 <= end; p += 4) {
        float2 e0 = srcRW[p], e1 = srcRW[p + 1], e2 = srcRW[p + 2], e3 = srcRW[p + 3];
        float v0 = x[__float_as_int(e0.x) * F + lane];
        float v1 = x[__float_as_int(e1.x) * F + lane];
        float v2 = x[__float_as_int(e2.x) * F + lane];
        float v3 = x[__float_as_int(e3.x) * F + lane];
        acc = fmaf(e0.y, v0, acc);
        acc = fmaf(e1.y, v1, acc);
        acc = fmaf(e2.y, v2, acc);
        acc = fmaf(e3.y, v3, acc);
    }
    for (; p < end; ++p) {
        float2 e = srcRW[p];
        acc = fmaf(e.y, x[__float_as_int(e.x) * F + lane], acc);
    }
    S[n * F + lane] = -dinv[n] * acc;
}

// ---- K5 v2: fused GEMMs + gating + output, 8x8 micro-tile, A transposed ----
__global__ __launch_bounds__(256) void fused_kernel(
    const float* __restrict__ x, float* sOut,
    const float* __restrict__ Wxz0, const float* __restrict__ Wxz1,
    const float* __restrict__ Wxh0, const float* __restrict__ Wxh1,
    const float* __restrict__ bxz, const float* __restrict__ bhz,
    const float* __restrict__ bxh, const float* __restrict__ bhh,
    const float* __restrict__ Wlin, const float* __restrict__ blin) {
    __shared__ float As[64 * ASTRIDE];  // [k][node], 33 KB
    __shared__ float Wc[32 * 128];      // 16 KB (also reused as Wlin[64][64])

    const int t = threadIdx.x;
    const int n0 = blockIdx.x * BN;
    const int ti = t >> 4;              // 0..15 -> node octet
    const int tj = t & 15;              // 0..15 -> col quad
    const int f0 = tj * 4;

    float zacc[8][4], hacc[8][4];
#pragma unroll
    for (int j = 0; j < 4; ++j) {
        float bz = bxz[f0 + j] + bhz[f0 + j];
        float bh = bxh[f0 + j] + bhh[f0 + j];
#pragma unroll
        for (int i = 0; i < 8; ++i) { zacc[i][j] = bz; hacc[i][j] = bh; }
    }

    const int sn = t & 127;             // staging node (invariant across reps)
    const int gn_s = n0 + sn;
    const int qb = t >> 7;              // 0/1

    for (int half = 0; half < 2; ++half) {
        const float* Abase = half ? (const float*)sOut : x;
        // stage A transposed: As[k][node]; lanes span nodes -> 2-way LDS, free
#pragma unroll
        for (int r = 0; r < 8; ++r) {
            int q = r * 2 + qb;         // k-quad 0..15
            float4 v = make_float4(0.f, 0.f, 0.f, 0.f);
            if (gn_s < N_NODES) v = *(const float4*)&Abase[gn_s * F + q * 4];
            As[(q * 4 + 0) * ASTRIDE + sn] = v.x;
            As[(q * 4 + 1) * ASTRIDE + sn] = v.y;
            As[(q * 4 + 2) * ASTRIDE + sn] = v.z;
            As[(q * 4 + 3) * ASTRIDE + sn] = v.w;
        }
        const float* Wz = half ? Wxz1 : Wxz0;
        const float* Wh = half ? Wxh1 : Wxh0;
        for (int wchunk = 0; wchunk < 2; ++wchunk) {
            const int kb = wchunk * 32;
            // stage Wc[kk][0..63]=Wz rows, [64..127]=Wh rows
#pragma unroll
            for (int r = 0; r < 4; ++r) {
                int idx = r * 256 + t;
                int cq = idx & 31;
                int kk = idx >> 5;
                const float* src = (cq < 16) ? &Wz[(kb + kk) * F + cq * 4]
                                             : &Wh[(kb + kk) * F + (cq - 16) * 4];
                *(float4*)&Wc[kk * 128 + cq * 4] = *(const float4*)src;
            }
            __syncthreads();
#pragma unroll 8
            for (int kk = 0; kk < 32; ++kk) {
                const int kl = kb + kk;
                float4 a0 = *(const float4*)&As[kl * ASTRIDE + ti * 8];
                float4 a1 = *(const float4*)&As[kl * ASTRIDE + ti * 8 + 4];
                float4 wz = *(const float4*)&Wc[kk * 128 + f0];
                float4 wh = *(const float4*)&Wc[kk * 128 + 64 + f0];
                float a[8] = {a0.x, a0.y, a0.z, a0.w, a1.x, a1.y, a1.z, a1.w};
#pragma unroll
                for (int i = 0; i < 8; ++i) {
                    zacc[i][0] = fmaf(a[i], wz.x, zacc[i][0]);
                    zacc[i][1] = fmaf(a[i], wz.y, zacc[i][1]);
                    zacc[i][2] = fmaf(a[i], wz.z, zacc[i][2]);
                    zacc[i][3] = fmaf(a[i], wz.w, zacc[i][3]);
                    hacc[i][0] = fmaf(a[i], wh.x, hacc[i][0]);
                    hacc[i][1] = fmaf(a[i], wh.y, hacc[i][1]);
                    hacc[i][2] = fmaf(a[i], wh.z, hacc[i][2]);
                    hacc[i][3] = fmaf(a[i], wh.w, hacc[i][3]);
                }
            }
            __syncthreads();
        }
    }

    // gating: R = relu((1-sigmoid(z)) * tanh(h)); write R^T into As[f][node]
#pragma unroll
    for (int j = 0; j < 4; ++j)
#pragma unroll
        for (int i = 0; i < 8; ++i) {
            float zz = 1.0f / (1.0f + __expf(-zacc[i][j]));
            float hh = tanhf(hacc[i][j]);
            float R = fmaxf((1.0f - zz) * hh, 0.0f);
            As[(f0 + j) * ASTRIDE + ti * 8 + i] = R;
        }
    // stage Wlin into Wc as [64][64]
#pragma unroll
    for (int r = 0; r < 4; ++r) {
        int idx = r * 256 + t;
        int cq = idx & 15;
        int kk = idx >> 4;              // 0..63
        *(float4*)&Wc[kk * 64 + cq * 4] = *(const float4*)&Wlin[kk * F + cq * 4];
    }
    __syncthreads();

    // out = R @ Wlin + blin
    float oacc[8][4];
#pragma unroll
    for (int j = 0; j < 4; ++j) {
        float bl = blin[f0 + j];
#pragma unroll
        for (int i = 0; i < 8; ++i) oacc[i][j] = bl;
    }
#pragma unroll 8
    for (int k = 0; k < 64; ++k) {
        float4 a0 = *(const float4*)&As[k * ASTRIDE + ti * 8];
        float4 a1 = *(const float4*)&As[k * ASTRIDE + ti * 8 + 4];
        float4 w = *(const float4*)&Wc[k * 64 + f0];
        float a[8] = {a0.x, a0.y, a0.z, a0.w, a1.x, a1.y, a1.z, a1.w};
#pragma unroll
        for (int i = 0; i < 8; ++i) {
            oacc[i][0] = fmaf(a[i], w.x, oacc[i][0]);
            oacc[i][1] = fmaf(a[i], w.y, oacc[i][1]);
            oacc[i][2] = fmaf(a[i], w.z, oacc[i][2]);
            oacc[i][3] = fmaf(a[i], w.w, oacc[i][3]);
        }
    }
#pragma unroll
    for (int i = 0; i < 8; ++i) {
        int gn = n0 + ti * 8 + i;
        if (gn < N_NODES) {
            float4 v = make_float4(oacc[i][0], oacc[i][1], oacc[i][2], oacc[i][3]);
            *(float4*)&sOut[gn * F + f0] = v;
        }
    }
}

// ---- fallback scatter (only if ws too small) ----
__global__ __launch_bounds__(256) void scatter_fb(const int* __restrict__ ei,
                                                  const float* __restrict__ ew,
                                                  const float* __restrict__ x,
                                                  const float* __restrict__ dinv,
                                                  float* S) {
    int e = blockIdx.x * 4 + (threadIdx.x >> 6);
    int lane = threadIdx.x & 63;
    if (e >= N_EDGES) return;
    int r = ei[e];
    int c = ei[N_EDGES + e];
    if (r == c) return;
    float nrm = -dinv[r] * ew[e] * dinv[c];
    atomicAdd(&S[c * F + lane], nrm * x[r * F + lane]);
}

extern "C" void kernel_launch(void* const* d_in, const int* in_sizes, int n_in,
                              void* d_out, int out_size, void* d_ws, size_t ws_size,
                              hipStream_t stream) {
    const float* x    = (const float*)d_in[0];
    const int*   ei   = (const int*)d_in[1];
    const float* ew   = (const float*)d_in[2];
    const float* Wxz0 = (const float*)d_in[3];
    const float* Wxz1 = (const float*)d_in[4];
    const float* bxz  = (const float*)d_in[5];
    const float* bhz  = (const float*)d_in[8];
    const float* Wxh0 = (const float*)d_in[15];
    const float* Wxh1 = (const float*)d_in[16];
    const float* bxh  = (const float*)d_in[17];
    const float* bhh  = (const float*)d_in[20];
    const float* Wlin = (const float*)d_in[21];
    const float* blin = (const float*)d_in[22];
    float* outp = (float*)d_out;  // doubles as S buffer

    // ws layout: [deg | cnt | dinv | offs(+1) | cursor | bsum | bbase | srcRW]
    float*  deg   = (float*)d_ws;
    int*    cnt   = (int*)(deg + NPAD);
    float*  dinv  = (float*)(cnt + NPAD);
    int*    offs  = (int*)(dinv + NPAD);
    int*    curs  = offs + NPAD;
    int*    bsum  = curs + NPAD;
    int*    bbase = bsum + 256;
    float2* srcRW = (float2*)(bbase + 256);   // offset NPAD*5+512 ints -> 8B aligned
    size_t needed = (size_t)NPAD * 5 * 4 + 2048 + (size_t)N_EDGES * 8 + 256;

    if (ws_size >= needed) {
        hipMemsetAsync(d_ws, 0, (size_t)NPAD * 2 * sizeof(float), stream);  // deg + cnt
        degcnt_kernel<<<(N_EDGES + 255) / 256, 256, 0, stream>>>(ei, ew, deg, cnt);
        reduce_kernel<<<NCHUNK, 256, 0, stream>>>(deg, dinv, cnt, bsum);
        scanb_kernel<<<1, 256, 0, stream>>>(bsum, bbase, &offs[N_NODES]);
        scanc_kernel<<<NCHUNK, 256, 0, stream>>>(cnt, bbase, offs, curs);
        fill_kernel<<<(N_EDGES + 255) / 256, 256, 0, stream>>>(ei, ew, dinv, curs, srcRW);
        gather_kernel<<<(N_NODES + 3) / 4, 256, 0, stream>>>(offs, srcRW, x, dinv, outp);
    } else {
        hipMemsetAsync(d_ws, 0, (size_t)NPAD * 2 * sizeof(float), stream);
        hipMemsetAsync(d_out, 0, (size_t)N_NODES * F * sizeof(float), stream);
        degcnt_kernel<<<(N_EDGES + 255) / 256, 256, 0, stream>>>(ei, ew, deg, cnt);
        reduce_kernel<<<NCHUNK, 256, 0, stream>>>(deg, dinv, cnt, cnt);
        scatter_fb<<<N_EDGES / 4, 256, 0, stream>>>(ei, ew, x, dinv, outp);
    }
    fused_kernel<<<(N_NODES + BN - 1) / BN, 256, 0, stream>>>(
        x, outp, Wxz0, Wxz1, Wxh0, Wxh1, bxz, bhz, bxh, bhh, Wlin, blin);
}

// Round 5
// 171.973 us; speedup vs baseline: 2.5837x; 1.2692x over previous
//
#include <hip/hip_runtime.h>

#define N_NODES 50000
#define N_EDGES 800000
#define F 64
#define NPAD 50048                      // N_NODES padded to multiple of 64
#define CAP 32                          // slots per node (Poisson(16) tail -> overflow list)
#define BN 128                          // nodes per fused block
#define ASTRIDE 132                     // 128 + 4 pad

// ---- K1: fused histogram + placement + deg ----
__global__ __launch_bounds__(256) void build_kernel(const int* __restrict__ ei,
                                                    const float* __restrict__ ew,
                                                    float* __restrict__ deg,
                                                    int* __restrict__ cnt,
                                                    int* __restrict__ ohead,
                                                    int* __restrict__ onxt,
                                                    uint2* __restrict__ slots) {
    int e = blockIdx.x * blockDim.x + threadIdx.x;
    if (e >= N_EDGES) return;
    int r = ei[e];
    int c = ei[N_EDGES + e];
    if (r == c) return;
    float w = ew[e];
    atomicAdd(&deg[r], w);
    int p = atomicAdd(&cnt[c], 1);
    if (p < CAP) {
        slots[c * CAP + p] = make_uint2((unsigned)r, __float_as_uint(w));
    } else {
        onxt[e] = atomicExch(&ohead[c], e);
    }
}

// ---- K2: dinv = deg>0 ? rsqrt(deg) : 0 ----
__global__ __launch_bounds__(256) void dinv_kernel(const float* __restrict__ deg,
                                                   float* __restrict__ dinv) {
    int n = blockIdx.x * blockDim.x + threadIdx.x;
    if (n >= N_NODES) return;
    float d = deg[n];
    dinv[n] = (d > 0.0f) ? rsqrtf(d) : 0.0f;
}

// ---- K3: per-node gather, one wave per node, no atomics ----
__global__ __launch_bounds__(256) void gather_kernel(const int* __restrict__ cnt,
                                                     const uint2* __restrict__ slots,
                                                     const int* __restrict__ ohead,
                                                     const int* __restrict__ onxt,
                                                     const int* __restrict__ ei,
                                                     const float* __restrict__ ew,
                                                     const float* __restrict__ dinv,
                                                     const float* __restrict__ x,
                                                     float* __restrict__ S) {
    int n = blockIdx.x * 4 + (threadIdx.x >> 6);
    int lane = threadIdx.x & 63;
    if (n >= N_NODES) return;
    int m = cnt[n];
    int ms = min(m, CAP);

    // lanes 0..31 hold slot j = lane; (lanes 32..63 mirror) -> 256B coalesced load
    uint2 myslot = slots[n * CAP + (lane & 31)];
    int myr = 0;
    float mywd = 0.0f;
    if ((lane & 31) < ms) {
        myr = (int)myslot.x;
        mywd = __uint_as_float(myslot.y) * dinv[myr];   // all dinv reads in flight at once
    }

    float acc = 0.0f;
    int i = 0;
    for (; i + 4 <= ms; i += 4) {
        int r0 = __shfl(myr, i + 0), r1 = __shfl(myr, i + 1);
        int r2 = __shfl(myr, i + 2), r3 = __shfl(myr, i + 3);
        float w0 = __shfl(mywd, i + 0), w1 = __shfl(mywd, i + 1);
        float w2 = __shfl(mywd, i + 2), w3 = __shfl(mywd, i + 3);
        float v0 = x[r0 * F + lane];
        float v1 = x[r1 * F + lane];
        float v2 = x[r2 * F + lane];
        float v3 = x[r3 * F + lane];
        acc = fmaf(w0, v0, acc);
        acc = fmaf(w1, v1, acc);
        acc = fmaf(w2, v2, acc);
        acc = fmaf(w3, v3, acc);
    }
    for (; i < ms; ++i) {
        int r = __shfl(myr, i);
        float wd = __shfl(mywd, i);
        acc = fmaf(wd, x[r * F + lane], acc);
    }
    if (m > CAP) {   // rare overflow: walk list (uniform addresses per wave)
        for (int e = ohead[n]; e >= 0; e = onxt[e]) {
            int r = ei[e];
            float wd = ew[e] * dinv[r];
            acc = fmaf(wd, x[r * F + lane], acc);
        }
    }
    S[n * F + lane] = -dinv[n] * acc;
}

// ---- K4: fused GEMMs + gating + output, 8x8 micro-tile, A transposed ----
__global__ __launch_bounds__(256) void fused_kernel(
    const float* __restrict__ x, float* sOut,
    const float* __restrict__ Wxz0, const float* __restrict__ Wxz1,
    const float* __restrict__ Wxh0, const float* __restrict__ Wxh1,
    const float* __restrict__ bxz, const float* __restrict__ bhz,
    const float* __restrict__ bxh, const float* __restrict__ bhh,
    const float* __restrict__ Wlin, const float* __restrict__ blin) {
    __shared__ float As[64 * ASTRIDE];  // [k][node], 33 KB
    __shared__ float Wc[32 * 128];      // 16 KB (also reused as Wlin[64][64])

    const int t = threadIdx.x;
    const int n0 = blockIdx.x * BN;
    const int ti = t >> 4;              // 0..15 -> node octet
    const int tj = t & 15;              // 0..15 -> col quad
    const int f0 = tj * 4;

    float zacc[8][4], hacc[8][4];
#pragma unroll
    for (int j = 0; j < 4; ++j) {
        float bz = bxz[f0 + j] + bhz[f0 + j];
        float bh = bxh[f0 + j] + bhh[f0 + j];
#pragma unroll
        for (int i = 0; i < 8; ++i) { zacc[i][j] = bz; hacc[i][j] = bh; }
    }

    const int sn = t & 127;
    const int gn_s = n0 + sn;
    const int qb = t >> 7;

    for (int half = 0; half < 2; ++half) {
        const float* Abase = half ? (const float*)sOut : x;
#pragma unroll
        for (int r = 0; r < 8; ++r) {
            int q = r * 2 + qb;
            float4 v = make_float4(0.f, 0.f, 0.f, 0.f);
            if (gn_s < N_NODES) v = *(const float4*)&Abase[gn_s * F + q * 4];
            As[(q * 4 + 0) * ASTRIDE + sn] = v.x;
            As[(q * 4 + 1) * ASTRIDE + sn] = v.y;
            As[(q * 4 + 2) * ASTRIDE + sn] = v.z;
            As[(q * 4 + 3) * ASTRIDE + sn] = v.w;
        }
        const float* Wz = half ? Wxz1 : Wxz0;
        const float* Wh = half ? Wxh1 : Wxh0;
        for (int wchunk = 0; wchunk < 2; ++wchunk) {
            const int kb = wchunk * 32;
#pragma unroll
            for (int r = 0; r < 4; ++r) {
                int idx = r * 256 + t;
                int cq = idx & 31;
                int kk = idx >> 5;
                const float* src = (cq < 16) ? &Wz[(kb + kk) * F + cq * 4]
                                             : &Wh[(kb + kk) * F + (cq - 16) * 4];
                *(float4*)&Wc[kk * 128 + cq * 4] = *(const float4*)src;
            }
            __syncthreads();
#pragma unroll 8
            for (int kk = 0; kk < 32; ++kk) {
                const int kl = kb + kk;
                float4 a0 = *(const float4*)&As[kl * ASTRIDE + ti * 8];
                float4 a1 = *(const float4*)&As[kl * ASTRIDE + ti * 8 + 4];
                float4 wz = *(const float4*)&Wc[kk * 128 + f0];
                float4 wh = *(const float4*)&Wc[kk * 128 + 64 + f0];
                float a[8] = {a0.x, a0.y, a0.z, a0.w, a1.x, a1.y, a1.z, a1.w};
#pragma unroll
                for (int i = 0; i < 8; ++i) {
                    zacc[i][0] = fmaf(a[i], wz.x, zacc[i][0]);
                    zacc[i][1] = fmaf(a[i], wz.y, zacc[i][1]);
                    zacc[i][2] = fmaf(a[i], wz.z, zacc[i][2]);
                    zacc[i][3] = fmaf(a[i], wz.w, zacc[i][3]);
                    hacc[i][0] = fmaf(a[i], wh.x, hacc[i][0]);
                    hacc[i][1] = fmaf(a[i], wh.y, hacc[i][1]);
                    hacc[i][2] = fmaf(a[i], wh.z, hacc[i][2]);
                    hacc[i][3] = fmaf(a[i], wh.w, hacc[i][3]);
                }
            }
            __syncthreads();
        }
    }

    // gating: R = relu((1-sigmoid(z)) * tanh(h)); write R^T into As[f][node]
#pragma unroll
    for (int j = 0; j < 4; ++j)
#pragma unroll
        for (int i = 0; i < 8; ++i) {
            float zz = 1.0f / (1.0f + __expf(-zacc[i][j]));
            float hh = tanhf(hacc[i][j]);
            float R = fmaxf((1.0f - zz) * hh, 0.0f);
            As[(f0 + j) * ASTRIDE + ti * 8 + i] = R;
        }
#pragma unroll
    for (int r = 0; r < 4; ++r) {
        int idx = r * 256 + t;
        int cq = idx & 15;
        int kk = idx >> 4;
        *(float4*)&Wc[kk * 64 + cq * 4] = *(const float4*)&Wlin[kk * F + cq * 4];
    }
    __syncthreads();

    float oacc[8][4];
#pragma unroll
    for (int j = 0; j < 4; ++j) {
        float bl = blin[f0 + j];
#pragma unroll
        for (int i = 0; i < 8; ++i) oacc[i][j] = bl;
    }
#pragma unroll 8
    for (int k = 0; k < 64; ++k) {
        float4 a0 = *(const float4*)&As[k * ASTRIDE + ti * 8];
        float4 a1 = *(const float4*)&As[k * ASTRIDE + ti * 8 + 4];
        float4 w = *(const float4*)&Wc[k * 64 + f0];
        float a[8] = {a0.x, a0.y, a0.z, a0.w, a1.x, a1.y, a1.z, a1.w};
#pragma unroll
        for (int i = 0; i < 8; ++i) {
            oacc[i][0] = fmaf(a[i], w.x, oacc[i][0]);
            oacc[i][1] = fmaf(a[i], w.y, oacc[i][1]);
            oacc[i][2] = fmaf(a[i], w.z, oacc[i][2]);
            oacc[i][3] = fmaf(a[i], w.w, oacc[i][3]);
        }
    }
#pragma unroll
    for (int i = 0; i < 8; ++i) {
        int gn = n0 + ti * 8 + i;
        if (gn < N_NODES) {
            float4 v = make_float4(oacc[i][0], oacc[i][1], oacc[i][2], oacc[i][3]);
            *(float4*)&sOut[gn * F + f0] = v;
        }
    }
}

// ---- fallback scatter (only if ws too small) ----
__global__ __launch_bounds__(256) void deg_fb(const int* __restrict__ ei,
                                              const float* __restrict__ ew,
                                              float* __restrict__ deg) {
    int e = blockIdx.x * blockDim.x + threadIdx.x;
    if (e >= N_EDGES) return;
    int r = ei[e];
    int c = ei[N_EDGES + e];
    if (r != c) atomicAdd(&deg[r], ew[e]);
}

__global__ __launch_bounds__(256) void scatter_fb(const int* __restrict__ ei,
                                                  const float* __restrict__ ew,
                                                  const float* __restrict__ x,
                                                  const float* __restrict__ dinv,
                                                  float* S) {
    int e = blockIdx.x * 4 + (threadIdx.x >> 6);
    int lane = threadIdx.x & 63;
    if (e >= N_EDGES) return;
    int r = ei[e];
    int c = ei[N_EDGES + e];
    if (r == c) return;
    float nrm = -dinv[r] * ew[e] * dinv[c];
    atomicAdd(&S[c * F + lane], nrm * x[r * F + lane]);
}

extern "C" void kernel_launch(void* const* d_in, const int* in_sizes, int n_in,
                              void* d_out, int out_size, void* d_ws, size_t ws_size,
                              hipStream_t stream) {
    const float* x    = (const float*)d_in[0];
    const int*   ei   = (const int*)d_in[1];
    const float* ew   = (const float*)d_in[2];
    const float* Wxz0 = (const float*)d_in[3];
    const float* Wxz1 = (const float*)d_in[4];
    const float* bxz  = (const float*)d_in[5];
    const float* bhz  = (const float*)d_in[8];
    const float* Wxh0 = (const float*)d_in[15];
    const float* Wxh1 = (const float*)d_in[16];
    const float* bxh  = (const float*)d_in[17];
    const float* bhh  = (const float*)d_in[20];
    const float* Wlin = (const float*)d_in[21];
    const float* blin = (const float*)d_in[22];
    float* outp = (float*)d_out;  // doubles as S buffer

    // ws layout: [deg | cnt | ohead | dinv | onxt | slots]
    float*  deg   = (float*)d_ws;
    int*    cnt   = (int*)(deg + NPAD);
    int*    ohead = cnt + NPAD;
    float*  dinv  = (float*)(ohead + NPAD);
    int*    onxt  = (int*)(dinv + NPAD);
    uint2*  slots = (uint2*)(onxt + N_EDGES);   // 8B-aligned (even # of ints before)
    size_t needed = (size_t)NPAD * 4 * 4 + (size_t)N_EDGES * 4
                  + (size_t)NPAD * CAP * 8 + 256;

    if (ws_size >= needed) {
        hipMemsetAsync(deg, 0, (size_t)NPAD * 2 * sizeof(float), stream);   // deg + cnt
        hipMemsetAsync(ohead, 0xFF, (size_t)NPAD * sizeof(int), stream);    // -1
        build_kernel<<<(N_EDGES + 255) / 256, 256, 0, stream>>>(
            ei, ew, deg, cnt, ohead, onxt, slots);
        dinv_kernel<<<(N_NODES + 255) / 256, 256, 0, stream>>>(deg, dinv);
        gather_kernel<<<(N_NODES + 3) / 4, 256, 0, stream>>>(
            cnt, slots, ohead, onxt, ei, ew, dinv, x, outp);
    } else {
        hipMemsetAsync(deg, 0, (size_t)NPAD * sizeof(float), stream);
        hipMemsetAsync(d_out, 0, (size_t)N_NODES * F * sizeof(float), stream);
        deg_fb<<<(N_EDGES + 255) / 256, 256, 0, stream>>>(ei, ew, deg);
        dinv_kernel<<<(N_NODES + 255) / 256, 256, 0, stream>>>(deg, dinv);
        scatter_fb<<<N_EDGES / 4, 256, 0, stream>>>(ei, ew, x, dinv, outp);
    }
    fused_kernel<<<(N_NODES + BN - 1) / BN, 256, 0, stream>>>(
        x, outp, Wxz0, Wxz1, Wxh0, Wxh1, bxz, bhz, bxh, bhh, Wlin, blin);
}

// Round 6
// 123.299 us; speedup vs baseline: 3.6036x; 1.3948x over previous
//
#include <hip/hip_runtime.h>

#define N_NODES 50000
#define N_EDGES 800000
#define F 64
#define NPAD 50048                       // N_NODES padded to multiple of 64
#define NBUCK 196                        // node buckets of 256 (50176 >= 50000)
#define NBLK 256                         // phase-A blocks
#define EPB (N_EDGES / NBLK)             // 3125 edges per phase-A block
#define BN 128                           // nodes per fused block
#define ASTRIDE 132                      // 128 + 4 pad

// ---- K1: per-block LDS histograms of row-bucket and col-bucket ----
__global__ __launch_bounds__(256) void count_kernel(const int* __restrict__ ei,
                                                    int* __restrict__ cntC,
                                                    int* __restrict__ cntR) {
    __shared__ int histC[NBUCK], histR[NBUCK];
    const int t = threadIdx.x, blk = blockIdx.x;
    for (int i = t; i < NBUCK; i += 256) { histC[i] = 0; histR[i] = 0; }
    __syncthreads();
    const int e0 = blk * EPB;
    for (int i = t; i < EPB; i += 256) {
        int e = e0 + i;
        int r = ei[e], c = ei[N_EDGES + e];
        if (r != c) {
            atomicAdd(&histC[c >> 8], 1);
            atomicAdd(&histR[r >> 8], 1);
        }
    }
    __syncthreads();
    for (int i = t; i < NBUCK; i += 256) {
        cntC[i * NBLK + blk] = histC[i];
        cntR[i * NBLK + blk] = histR[i];
    }
}

// ---- K2a: per-bucket exclusive scan over NBLK block-counts (in place) ----
__global__ __launch_bounds__(256) void scan1_kernel(int* __restrict__ cntC,
                                                    int* __restrict__ cntR,
                                                    int* __restrict__ btC,
                                                    int* __restrict__ btR) {
    __shared__ int wsum[4];
    const int t = threadIdx.x, g = blockIdx.x;
    int* cnt = (g < NBUCK) ? cntC : cntR;
    int* bt  = (g < NBUCK) ? btC : btR;
    const int bucket = (g < NBUCK) ? g : g - NBUCK;
    const int lane = t & 63, wid = t >> 6;
    int v = cnt[bucket * NBLK + t];
    int s = v;
#pragma unroll
    for (int d = 1; d < 64; d <<= 1) {
        int u = __shfl_up(s, d);
        if (lane >= d) s += u;
    }
    if (lane == 63) wsum[wid] = s;
    __syncthreads();
    int wbase = 0;
    for (int w = 0; w < wid; ++w) wbase += wsum[w];
    cnt[bucket * NBLK + t] = wbase + s - v;       // exclusive within bucket
    if (t == 255) bt[bucket] = wbase + s;         // bucket total
}

// ---- K2b (1 block): scan bucket totals -> bucket bases; write offs[N] ----
__global__ __launch_bounds__(256) void scan2_kernel(const int* __restrict__ btC,
                                                    const int* __restrict__ btR,
                                                    int* __restrict__ bbC,
                                                    int* __restrict__ bbR,
                                                    int* __restrict__ offs) {
    __shared__ int wsum[4];
    const int t = threadIdx.x;
    const int lane = t & 63, wid = t >> 6;
    // scan C
    {
        int v = (t < NBUCK) ? btC[t] : 0;
        int s = v;
#pragma unroll
        for (int d = 1; d < 64; d <<= 1) {
            int u = __shfl_up(s, d);
            if (lane >= d) s += u;
        }
        if (lane == 63) wsum[wid] = s;
        __syncthreads();
        int wbase = 0;
        for (int w = 0; w < wid; ++w) wbase += wsum[w];
        if (t < NBUCK) bbC[t] = wbase + s - v;
        if (t == 255) { bbC[NBUCK] = wbase + s; offs[N_NODES] = wbase + s; }
        __syncthreads();
    }
    // scan R
    {
        int v = (t < NBUCK) ? btR[t] : 0;
        int s = v;
#pragma unroll
        for (int d = 1; d < 64; d <<= 1) {
            int u = __shfl_up(s, d);
            if (lane >= d) s += u;
        }
        if (lane == 63) wsum[wid] = s;
        __syncthreads();
        int wbase = 0;
        for (int w = 0; w < wid; ++w) wbase += wsum[w];
        if (t < NBUCK) bbR[t] = wbase + s - v;
        if (t == 255) bbR[NBUCK] = wbase + s;
    }
}

// ---- K3: place edges into bucket-partitioned arrays (LDS cursors only) ----
__global__ __launch_bounds__(256) void place_kernel(const int* __restrict__ ei,
                                                    const float* __restrict__ ew,
                                                    const int* __restrict__ cntC,
                                                    const int* __restrict__ cntR,
                                                    const int* __restrict__ bbC,
                                                    const int* __restrict__ bbR,
                                                    uint2* __restrict__ colPart,
                                                    uint2* __restrict__ rowPart) {
    __shared__ int cursC[NBUCK], cursR[NBUCK];
    const int t = threadIdx.x, blk = blockIdx.x;
    for (int i = t; i < NBUCK; i += 256) {
        cursC[i] = bbC[i] + cntC[i * NBLK + blk];
        cursR[i] = bbR[i] + cntR[i * NBLK + blk];
    }
    __syncthreads();
    const int e0 = blk * EPB;
    for (int i = t; i < EPB; i += 256) {
        int e = e0 + i;
        int r = ei[e], c = ei[N_EDGES + e];
        if (r == c) continue;
        unsigned wbits = __float_as_uint(ew[e]);
        int pC = atomicAdd(&cursC[c >> 8], 1);
        colPart[pC] = make_uint2((unsigned)r | ((unsigned)(c & 255) << 16), wbits);
        int pR = atomicAdd(&cursR[r >> 8], 1);
        rowPart[pR] = make_uint2((unsigned)(r & 255), wbits);
    }
}

// ---- K4: per-bucket deg reduction (LDS fp32) -> dinv ----
__global__ __launch_bounds__(256) void rowB_kernel(const uint2* __restrict__ rowPart,
                                                   const int* __restrict__ bbR,
                                                   float* __restrict__ dinv) {
    __shared__ float degL[256];
    const int t = threadIdx.x, b = blockIdx.x;
    degL[t] = 0.0f;
    __syncthreads();
    const int start = bbR[b], end = bbR[b + 1];
    for (int i = start + t; i < end; i += 256) {
        uint2 v = rowPart[i];
        atomicAdd(&degL[v.x], __uint_as_float(v.y));
    }
    __syncthreads();
    int n = b * 256 + t;
    if (n < N_NODES) {
        float d = degL[t];
        dinv[n] = (d > 0.0f) ? rsqrtf(d) : 0.0f;
    }
}

// ---- K5: per-bucket CSR build; fold dinv[row] into weight ----
__global__ __launch_bounds__(256) void colB_kernel(const uint2* __restrict__ colPart,
                                                   const int* __restrict__ bbC,
                                                   const float* __restrict__ dinv,
                                                   int* __restrict__ offs,
                                                   uint2* __restrict__ edgesOut) {
    __shared__ int cntL[256];
    __shared__ int curL[256];
    __shared__ int wsum[4];
    const int t = threadIdx.x, b = blockIdx.x;
    const int lane = t & 63, wid = t >> 6;
    const int start = bbC[b], end = bbC[b + 1];
    cntL[t] = 0;
    __syncthreads();
    for (int i = start + t; i < end; i += 256) {
        uint2 v = colPart[i];
        atomicAdd(&cntL[(v.x >> 16) & 255], 1);
    }
    __syncthreads();
    int v = cntL[t];
    int s = v;
#pragma unroll
    for (int d = 1; d < 64; d <<= 1) {
        int u = __shfl_up(s, d);
        if (lane >= d) s += u;
    }
    if (lane == 63) wsum[wid] = s;
    __syncthreads();
    int wbase = 0;
    for (int w = 0; w < wid; ++w) wbase += wsum[w];
    int excl = wbase + s - v;
    curL[t] = excl;
    int n = b * 256 + t;
    if (n < N_NODES) offs[n] = start + excl;
    __syncthreads();
    for (int i = start + t; i < end; i += 256) {
        uint2 e = colPart[i];
        int cl = (e.x >> 16) & 255;
        int p = atomicAdd(&curL[cl], 1);
        int r = e.x & 0xFFFF;
        float wd = __uint_as_float(e.y) * dinv[r];
        edgesOut[start + p] = make_uint2((unsigned)r, __float_as_uint(wd));
    }
}

// ---- K6: CSR gather, one wave per node, coalesced edge loads + shfl ----
__global__ __launch_bounds__(256) void gather_kernel(const int* __restrict__ offs,
                                                     const uint2* __restrict__ edgesOut,
                                                     const float* __restrict__ dinv,
                                                     const float* __restrict__ x,
                                                     float* __restrict__ S) {
    int n = blockIdx.x * 4 + (threadIdx.x >> 6);
    int lane = threadIdx.x & 63;
    if (n >= N_NODES) return;
    int p = offs[n], end = offs[n + 1];
    float acc = 0.0f;
    for (int base = p; base < end; base += 32) {
        int rem = end - base;
        int sl = lane & 31;
        uint2 ev = make_uint2(0u, 0u);
        if (sl < rem) ev = edgesOut[base + sl];
        int myr = (int)ev.x;
        float mwd = __uint_as_float(ev.y);
        int cnt = min(rem, 32);
        int i = 0;
        for (; i + 4 <= cnt; i += 4) {
            int r0 = __shfl(myr, i + 0), r1 = __shfl(myr, i + 1);
            int r2 = __shfl(myr, i + 2), r3 = __shfl(myr, i + 3);
            float w0 = __shfl(mwd, i + 0), w1 = __shfl(mwd, i + 1);
            float w2 = __shfl(mwd, i + 2), w3 = __shfl(mwd, i + 3);
            float v0 = x[r0 * F + lane];
            float v1 = x[r1 * F + lane];
            float v2 = x[r2 * F + lane];
            float v3 = x[r3 * F + lane];
            acc = fmaf(w0, v0, acc);
            acc = fmaf(w1, v1, acc);
            acc = fmaf(w2, v2, acc);
            acc = fmaf(w3, v3, acc);
        }
        for (; i < cnt; ++i) {
            int r = __shfl(myr, i);
            float wd = __shfl(mwd, i);
            acc = fmaf(wd, x[r * F + lane], acc);
        }
    }
    S[n * F + lane] = -dinv[n] * acc;
}

// ---- K7: fused GEMMs + gating + output, 8x8 micro-tile, A transposed ----
__global__ __launch_bounds__(256) void fused_kernel(
    const float* __restrict__ x, float* sOut,
    const float* __restrict__ Wxz0, const float* __restrict__ Wxz1,
    const float* __restrict__ Wxh0, const float* __restrict__ Wxh1,
    const float* __restrict__ bxz, const float* __restrict__ bhz,
    const float* __restrict__ bxh, const float* __restrict__ bhh,
    const float* __restrict__ Wlin, const float* __restrict__ blin) {
    __shared__ float As[64 * ASTRIDE];  // [k][node], 33 KB
    __shared__ float Wc[32 * 128];      // 16 KB (reused as Wlin[64][64])

    const int t = threadIdx.x;
    const int n0 = blockIdx.x * BN;
    const int ti = t >> 4;
    const int tj = t & 15;
    const int f0 = tj * 4;

    float zacc[8][4], hacc[8][4];
#pragma unroll
    for (int j = 0; j < 4; ++j) {
        float bz = bxz[f0 + j] + bhz[f0 + j];
        float bh = bxh[f0 + j] + bhh[f0 + j];
#pragma unroll
        for (int i = 0; i < 8; ++i) { zacc[i][j] = bz; hacc[i][j] = bh; }
    }

    const int sn = t & 127;
    const int gn_s = n0 + sn;
    const int qb = t >> 7;

    for (int half = 0; half < 2; ++half) {
        const float* Abase = half ? (const float*)sOut : x;
#pragma unroll
        for (int r = 0; r < 8; ++r) {
            int q = r * 2 + qb;
            float4 v = make_float4(0.f, 0.f, 0.f, 0.f);
            if (gn_s < N_NODES) v = *(const float4*)&Abase[gn_s * F + q * 4];
            As[(q * 4 + 0) * ASTRIDE + sn] = v.x;
            As[(q * 4 + 1) * ASTRIDE + sn] = v.y;
            As[(q * 4 + 2) * ASTRIDE + sn] = v.z;
            As[(q * 4 + 3) * ASTRIDE + sn] = v.w;
        }
        const float* Wz = half ? Wxz1 : Wxz0;
        const float* Wh = half ? Wxh1 : Wxh0;
        for (int wchunk = 0; wchunk < 2; ++wchunk) {
            const int kb = wchunk * 32;
#pragma unroll
            for (int r = 0; r < 4; ++r) {
                int idx = r * 256 + t;
                int cq = idx & 31;
                int kk = idx >> 5;
                const float* src = (cq < 16) ? &Wz[(kb + kk) * F + cq * 4]
                                             : &Wh[(kb + kk) * F + (cq - 16) * 4];
                *(float4*)&Wc[kk * 128 + cq * 4] = *(const float4*)src;
            }
            __syncthreads();
#pragma unroll 8
            for (int kk = 0; kk < 32; ++kk) {
                const int kl = kb + kk;
                float4 a0 = *(const float4*)&As[kl * ASTRIDE + ti * 8];
                float4 a1 = *(const float4*)&As[kl * ASTRIDE + ti * 8 + 4];
                float4 wz = *(const float4*)&Wc[kk * 128 + f0];
                float4 wh = *(const float4*)&Wc[kk * 128 + 64 + f0];
                float a[8] = {a0.x, a0.y, a0.z, a0.w, a1.x, a1.y, a1.z, a1.w};
#pragma unroll
                for (int i = 0; i < 8; ++i) {
                    zacc[i][0] = fmaf(a[i], wz.x, zacc[i][0]);
                    zacc[i][1] = fmaf(a[i], wz.y, zacc[i][1]);
                    zacc[i][2] = fmaf(a[i], wz.z, zacc[i][2]);
                    zacc[i][3] = fmaf(a[i], wz.w, zacc[i][3]);
                    hacc[i][0] = fmaf(a[i], wh.x, hacc[i][0]);
                    hacc[i][1] = fmaf(a[i], wh.y, hacc[i][1]);
                    hacc[i][2] = fmaf(a[i], wh.z, hacc[i][2]);
                    hacc[i][3] = fmaf(a[i], wh.w, hacc[i][3]);
                }
            }
            __syncthreads();
        }
    }

#pragma unroll
    for (int j = 0; j < 4; ++j)
#pragma unroll
        for (int i = 0; i < 8; ++i) {
            float zz = 1.0f / (1.0f + __expf(-zacc[i][j]));
            float hh = tanhf(hacc[i][j]);
            float R = fmaxf((1.0f - zz) * hh, 0.0f);
            As[(f0 + j) * ASTRIDE + ti * 8 + i] = R;
        }
#pragma unroll
    for (int r = 0; r < 4; ++r) {
        int idx = r * 256 + t;
        int cq = idx & 15;
        int kk = idx >> 4;
        *(float4*)&Wc[kk * 64 + cq * 4] = *(const float4*)&Wlin[kk * F + cq * 4];
    }
    __syncthreads();

    float oacc[8][4];
#pragma unroll
    for (int j = 0; j < 4; ++j) {
        float bl = blin[f0 + j];
#pragma unroll
        for (int i = 0; i < 8; ++i) oacc[i][j] = bl;
    }
#pragma unroll 8
    for (int k = 0; k < 64; ++k) {
        float4 a0 = *(const float4*)&As[k * ASTRIDE + ti * 8];
        float4 a1 = *(const float4*)&As[k * ASTRIDE + ti * 8 + 4];
        float4 w = *(const float4*)&Wc[k * 64 + f0];
        float a[8] = {a0.x, a0.y, a0.z, a0.w, a1.x, a1.y, a1.z, a1.w};
#pragma unroll
        for (int i = 0; i < 8; ++i) {
            oacc[i][0] = fmaf(a[i], w.x, oacc[i][0]);
            oacc[i][1] = fmaf(a[i], w.y, oacc[i][1]);
            oacc[i][2] = fmaf(a[i], w.z, oacc[i][2]);
            oacc[i][3] = fmaf(a[i], w.w, oacc[i][3]);
        }
    }
#pragma unroll
    for (int i = 0; i < 8; ++i) {
        int gn = n0 + ti * 8 + i;
        if (gn < N_NODES) {
            float4 v = make_float4(oacc[i][0], oacc[i][1], oacc[i][2], oacc[i][3]);
            *(float4*)&sOut[gn * F + f0] = v;
        }
    }
}

// ---- fallback path (ws too small): atomic scatter ----
__global__ __launch_bounds__(256) void deg_fb(const int* __restrict__ ei,
                                              const float* __restrict__ ew,
                                              float* __restrict__ deg) {
    int e = blockIdx.x * blockDim.x + threadIdx.x;
    if (e >= N_EDGES) return;
    int r = ei[e];
    int c = ei[N_EDGES + e];
    if (r != c) atomicAdd(&deg[r], ew[e]);
}

__global__ __launch_bounds__(256) void dinv_kernel(const float* __restrict__ deg,
                                                   float* __restrict__ dinv) {
    int n = blockIdx.x * blockDim.x + threadIdx.x;
    if (n >= N_NODES) return;
    float d = deg[n];
    dinv[n] = (d > 0.0f) ? rsqrtf(d) : 0.0f;
}

__global__ __launch_bounds__(256) void scatter_fb(const int* __restrict__ ei,
                                                  const float* __restrict__ ew,
                                                  const float* __restrict__ x,
                                                  const float* __restrict__ dinv,
                                                  float* S) {
    int e = blockIdx.x * 4 + (threadIdx.x >> 6);
    int lane = threadIdx.x & 63;
    if (e >= N_EDGES) return;
    int r = ei[e];
    int c = ei[N_EDGES + e];
    if (r == c) return;
    float nrm = -dinv[r] * ew[e] * dinv[c];
    atomicAdd(&S[c * F + lane], nrm * x[r * F + lane]);
}

extern "C" void kernel_launch(void* const* d_in, const int* in_sizes, int n_in,
                              void* d_out, int out_size, void* d_ws, size_t ws_size,
                              hipStream_t stream) {
    const float* x    = (const float*)d_in[0];
    const int*   ei   = (const int*)d_in[1];
    const float* ew   = (const float*)d_in[2];
    const float* Wxz0 = (const float*)d_in[3];
    const float* Wxz1 = (const float*)d_in[4];
    const float* bxz  = (const float*)d_in[5];
    const float* bhz  = (const float*)d_in[8];
    const float* Wxh0 = (const float*)d_in[15];
    const float* Wxh1 = (const float*)d_in[16];
    const float* bxh  = (const float*)d_in[17];
    const float* bhh  = (const float*)d_in[20];
    const float* Wlin = (const float*)d_in[21];
    const float* blin = (const float*)d_in[22];
    float* outp = (float*)d_out;  // doubles as S buffer

    // ws layout (ints first, all even counts -> uint2 arrays 8B-aligned)
    int*    cntC  = (int*)d_ws;                 // NBUCK*NBLK
    int*    cntR  = cntC + NBUCK * NBLK;        // NBUCK*NBLK
    int*    btC   = cntR + NBUCK * NBLK;        // 256
    int*    btR   = btC + 256;                  // 256
    int*    bbC   = btR + 256;                  // 256 (NBUCK+1 used)
    int*    bbR   = bbC + 256;                  // 256
    int*    offs  = bbR + 256;                  // NPAD+64
    float*  dinv  = (float*)(offs + NPAD + 64); // NPAD
    uint2*  colPart  = (uint2*)(dinv + NPAD);
    uint2*  rowPart  = colPart + N_EDGES;
    uint2*  edgesOut = rowPart + N_EDGES;
    size_t needed = (size_t)(2 * NBUCK * NBLK + 1024 + NPAD + 64 + NPAD) * 4
                  + (size_t)N_EDGES * 3 * 8 + 256;

    if (ws_size >= needed) {
        count_kernel<<<NBLK, 256, 0, stream>>>(ei, cntC, cntR);
        scan1_kernel<<<2 * NBUCK, 256, 0, stream>>>(cntC, cntR, btC, btR);
        scan2_kernel<<<1, 256, 0, stream>>>(btC, btR, bbC, bbR, offs);
        place_kernel<<<NBLK, 256, 0, stream>>>(ei, ew, cntC, cntR, bbC, bbR,
                                               colPart, rowPart);
        rowB_kernel<<<NBUCK, 256, 0, stream>>>(rowPart, bbR, dinv);
        colB_kernel<<<NBUCK, 256, 0, stream>>>(colPart, bbC, dinv, offs, edgesOut);
        gather_kernel<<<(N_NODES + 3) / 4, 256, 0, stream>>>(offs, edgesOut, dinv,
                                                             x, outp);
    } else {
        float* deg = (float*)d_ws;
        float* dv  = deg + NPAD;
        hipMemsetAsync(deg, 0, (size_t)NPAD * sizeof(float), stream);
        hipMemsetAsync(d_out, 0, (size_t)N_NODES * F * sizeof(float), stream);
        deg_fb<<<(N_EDGES + 255) / 256, 256, 0, stream>>>(ei, ew, deg);
        dinv_kernel<<<(N_NODES + 255) / 256, 256, 0, stream>>>(deg, dv);
        scatter_fb<<<N_EDGES / 4, 256, 0, stream>>>(ei, ew, x, dv, outp);
    }
    fused_kernel<<<(N_NODES + BN - 1) / BN, 256, 0, stream>>>(
        x, outp, Wxz0, Wxz1, Wxh0, Wxh1, bxz, bhz, bxh, bhh, Wlin, blin);
}